// Round 13
// baseline (183.142 us; speedup 1.0000x reference)
//
#include <hip/hip_runtime.h>
#include <hip/hip_bf16.h>
#include <hip/hip_fp8.h>

#define D_ 128
#define H_ 2
#define L_ 4
#define HD_ 256   // H_*D_
// (1/sqrt(128)) * log2(e): logits kept in base-2 domain, exp2f = bare v_exp_f32
#define P2L 0.12751743f

typedef __attribute__((ext_vector_type(8))) short bf16x8;
typedef __attribute__((ext_vector_type(4))) float f32x4;
typedef __attribute__((ext_vector_type(2))) float f32x2;

__device__ __forceinline__ unsigned short f2bf(float x) {
    __hip_bfloat16 b = __float2bfloat16(x);
    return *reinterpret_cast<unsigned short*>(&b);
}
__device__ __forceinline__ float bf2f(unsigned short u) {
    return __uint_as_float(((unsigned)u) << 16);
}
__device__ __forceinline__ unsigned char f2fp8(float x) {
    __hip_fp8_e4m3 t(x);
    return (unsigned char)t.__x;
}
__device__ __forceinline__ float fp82f(unsigned u) {
    __hip_fp8_e4m3 t; t.__x = (__hip_fp8_storage_t)u; return (float)t;
}
// unpack 8 interleaved bf16 (d*2+h layout) -> h0[4], h1[4]
__device__ __forceinline__ void unpack_il(const uint4 v, float* h0, float* h1) {
    const unsigned short* u = reinterpret_cast<const unsigned short*>(&v);
#pragma unroll
    for (int j = 0; j < 4; ++j) { h0[j] = bf2f(u[2 * j]); h1[j] = bf2f(u[2 * j + 1]); }
}

// ---------- K1: prep (nf->bf16+fp8, W->Wb) AND hist, fused by block range ----------
#define HIST_BLOCKS 512
__global__ __launch_bounds__(256)
void prep_hist_kernel(const float* __restrict__ nf,
                      const float* __restrict__ Wq, const float* __restrict__ Wk,
                      const float* __restrict__ Wv, const int* __restrict__ dst,
                      unsigned short* __restrict__ nfb, unsigned char* __restrict__ nf8,
                      unsigned short* __restrict__ Wb, int* __restrict__ counts,
                      int n4, int E_) {
    const int nfbB = (n4 + 255) / 256;
    const int bid = blockIdx.x;
    if (bid < nfbB) {
        const int i = bid * 256 + threadIdx.x;
        if (i < n4) {
            const float4 v = reinterpret_cast<const float4*>(nf)[i];
            ushort4 o;
            o.x = f2bf(v.x); o.y = f2bf(v.y); o.z = f2bf(v.z); o.w = f2bf(v.w);
            reinterpret_cast<ushort4*>(nfb)[i] = o;
            const unsigned p8 = (unsigned)f2fp8(v.x) | ((unsigned)f2fp8(v.y) << 8) |
                                ((unsigned)f2fp8(v.z) << 16) | ((unsigned)f2fp8(v.w) << 24);
            reinterpret_cast<unsigned*>(nf8)[i] = p8;
        }
    } else if (bid < nfbB + 384) {
        const int b = bid - nfbB;                     // 0..383
        const int n = b * 2 + (threadIdx.x >> 7);     // 0..767
        const int k = threadIdx.x & 127;
        const float* W = (n < 256) ? Wq : (n < 512) ? Wk : Wv;
        const int c = n & 255;
        Wb[(size_t)n * 128 + k] = f2bf(W[(size_t)k * HD_ + c]);
    } else {
        const int b = bid - nfbB - 384;               // 0..HIST_BLOCKS-1
        const int nquad = E_ >> 2;
        for (int i = b * 256 + threadIdx.x; i < nquad; i += HIST_BLOCKS * 256) {
            const int4 d4 = reinterpret_cast<const int4*>(dst)[i];
            atomicAdd(&counts[d4.x], 1);
            atomicAdd(&counts[d4.y], 1);
            atomicAdd(&counts[d4.z], 1);
            atomicAdd(&counts[d4.w], 1);
        }
        if (b == 0 && (int)threadIdx.x < (E_ & 3))
            atomicAdd(&counts[dst[(E_ & ~3) + threadIdx.x]], 1);
    }
}

// ---------- K2: scan1 + scan2 fused (last workgroup finalizes chunk sums) ----------
__global__ __launch_bounds__(256)
void scan12_kernel(const int* __restrict__ counts, int* __restrict__ offs,
                   int* __restrict__ blksum, int* __restrict__ ticket,
                   int n, int nblk) {
    __shared__ int sdata[256];
    __shared__ int isLast;
    const int t = threadIdx.x;
    const int base = blockIdx.x * 1024;
    int v[4]; int sum = 0;
#pragma unroll
    for (int j = 0; j < 4; ++j) {
        int idx = base + t * 4 + j;
        v[j] = (idx < n) ? counts[idx] : 0;
        sum += v[j];
    }
    sdata[t] = sum;
    __syncthreads();
    for (int off = 1; off < 256; off <<= 1) {
        int x = (t >= off) ? sdata[t - off] : 0;
        __syncthreads();
        sdata[t] += x;
        __syncthreads();
    }
    if (t == 255) blksum[blockIdx.x] = sdata[255];
    int run = sdata[t] - sum;
#pragma unroll
    for (int j = 0; j < 4; ++j) {
        int idx = base + t * 4 + j;
        if (idx < n) offs[idx] = run;
        run += v[j];
    }

    // last workgroup to finish runs the (tiny) scan over chunk sums
    __threadfence();
    if (t == 0) isLast = (atomicAdd(ticket, 1) == (int)gridDim.x - 1);
    __syncthreads();
    if (isLast && t < 64) {
        __threadfence();
        const int lane = t;
        int carry = 0;
        for (int b2 = 0; b2 < nblk; b2 += 64) {
            const int idx = b2 + lane;
            int vv = (idx < nblk) ? blksum[idx] : 0;
            int inc = vv;
#pragma unroll
            for (int off = 1; off < 64; off <<= 1) {
                int x = __shfl_up(inc, off, 64);
                if (lane >= off) inc += x;
            }
            if (idx < nblk) blksum[idx] = carry + inc - vv;   // exclusive
            carry += __shfl(inc, 63, 64);
        }
    }
}

// ---------- K3: MFMA QKV (64 rows/block) AND scatter (32B records), fused ----------
#define SCAT_BLOCKS 1024
#define QROWS 64
__global__ __launch_bounds__(256)
void qkv_scatter_kernel(const unsigned short* __restrict__ nfb,
                        const unsigned short* __restrict__ Wb,
                        unsigned short* __restrict__ Qil,
                        unsigned short* __restrict__ KVil,   // [node][512]: K il | V il
                        const int* __restrict__ dst, const int* __restrict__ src,
                        const int* __restrict__ mp, int* __restrict__ offs,
                        const int* __restrict__ blksum,
                        int* __restrict__ recs,             // [E][8] ints (32B records)
                        int n_nodes, int E_, int qkv_blocks) {
    __shared__ unsigned short sS[QROWS][264];

    if ((int)blockIdx.x >= qkv_blocks) {
        // ---- scatter: sort edge payload by dst; one 32B record per edge ----
        const int b = blockIdx.x - qkv_blocks;
        for (int i = b * 256 + threadIdx.x; i < E_; i += SCAT_BLOCKS * 256) {
            const int d = dst[i];
            const int pos = atomicAdd(&offs[d], 1) + blksum[d >> 10];
            const int4 m4 = *reinterpret_cast<const int4*>(&mp[(size_t)i * L_]);
            uint4 u0;
            u0.x = (unsigned)src[i]; u0.y = (unsigned)m4.x;
            u0.z = (unsigned)m4.y;   u0.w = (unsigned)m4.z;
            *reinterpret_cast<uint4*>(recs + (size_t)pos * 8) = u0;
            recs[(size_t)pos * 8 + 4] = m4.w;
        }
        return;
    }

    // ---- qkv: block owns 64 node-rows ----
    const int tid  = threadIdx.x;
    const int lane = tid & 63;
    const int wv   = tid >> 6;
    const int m0   = blockIdx.x * QROWS;
    const int r16  = lane & 15;
    const int kg   = lane >> 4;

    bf16x8 afrag[4][4];
#pragma unroll
    for (int ms = 0; ms < 4; ++ms) {
        int arow = m0 + ms * 16 + r16;
        if (arow >= n_nodes) arow = n_nodes - 1;
        const unsigned short* aptr = nfb + (size_t)arow * D_ + kg * 8;
#pragma unroll
        for (int kb = 0; kb < 4; ++kb)
            afrag[ms][kb] = *reinterpret_cast<const bf16x8*>(aptr + kb * 32);
    }

    for (int p = 0; p < 3; ++p) {           // phase: 0=Q, 1=K, 2=V
#pragma unroll
        for (int j = 0; j < 4; ++j) {
            const int n0 = p * 256 + (wv * 4 + j) * 16;
            const unsigned short* bptr = Wb + (size_t)(n0 + r16) * D_ + kg * 8;
            bf16x8 b0 = *reinterpret_cast<const bf16x8*>(bptr);
            bf16x8 b1 = *reinterpret_cast<const bf16x8*>(bptr + 32);
            bf16x8 b2 = *reinterpret_cast<const bf16x8*>(bptr + 64);
            bf16x8 b3 = *reinterpret_cast<const bf16x8*>(bptr + 96);
            f32x4 acc[4];
#pragma unroll
            for (int ms = 0; ms < 4; ++ms) { acc[ms] = {0.f, 0.f, 0.f, 0.f}; }
#pragma unroll
            for (int ms = 0; ms < 4; ++ms) {
                acc[ms] = __builtin_amdgcn_mfma_f32_16x16x32_bf16(afrag[ms][0], b0, acc[ms], 0, 0, 0);
                acc[ms] = __builtin_amdgcn_mfma_f32_16x16x32_bf16(afrag[ms][1], b1, acc[ms], 0, 0, 0);
                acc[ms] = __builtin_amdgcn_mfma_f32_16x16x32_bf16(afrag[ms][2], b2, acc[ms], 0, 0, 0);
                acc[ms] = __builtin_amdgcn_mfma_f32_16x16x32_bf16(afrag[ms][3], b3, acc[ms], 0, 0, 0);
            }
            const int ln = (n0 & 255) + r16;                   // local col 0..255
            const int il = ((ln & 127) << 1) | ((ln >> 7) & 1);
#pragma unroll
            for (int ms = 0; ms < 4; ++ms)
#pragma unroll
                for (int jj = 0; jj < 4; ++jj)
                    sS[ms * 16 + kg * 4 + jj][il] = f2bf(acc[ms][jj]);
        }
        __syncthreads();
        // flush QROWS rows x 256 cols (uint2 = 4 bf16)
        for (int i2 = tid; i2 < QROWS * 64; i2 += 256) {
            const int r = i2 >> 6, c4 = i2 & 63;
            const int node = m0 + r;
            if (node < n_nodes) {
                const uint2 val = *reinterpret_cast<const uint2*>(&sS[r][c4 * 4]);
                if (p == 0)
                    *reinterpret_cast<uint2*>(&Qil[(size_t)node * HD_ + c4 * 4]) = val;
                else if (p == 1)
                    *reinterpret_cast<uint2*>(&KVil[(size_t)node * 512 + c4 * 4]) = val;
                else
                    *reinterpret_cast<uint2*>(&KVil[(size_t)node * 512 + 256 + c4 * 4]) = val;
            }
        }
        __syncthreads();
    }
}

// ---------- K4: fused per-node, ONE wave per block (perfect load balance) ----------
__global__ __launch_bounds__(64)
void node_fused_kernel(const unsigned char* __restrict__ nf8,
                       const unsigned short* __restrict__ Qil,
                       const unsigned short* __restrict__ KVil,
                       const int* __restrict__ recs,    // [E][8] ints
                       const int* __restrict__ ends,    // chunk-local ends
                       const int* __restrict__ blksum,  // chunk bases
                       const int* __restrict__ counts,
                       float* __restrict__ out,
                       int n_nodes) {
    const int lane = threadIdx.x;
    const int half = lane >> 5;          // sub-wave id
    const int sl   = lane & 31;          // sub-lane: owns dims 4sl..4sl+3
    const int n = blockIdx.x;
    if (n >= n_nodes) return;

    const int deg = counts[n];
    const int end = ends[n] + blksum[n >> 10];
    const int start = end - deg;
    float* o = out + (size_t)n * HD_;

    if (deg == 0) {
        const float4 z = {0.f, 0.f, 0.f, 0.f};
        *reinterpret_cast<float4*>(&o[half * D_ + sl * 4]) = z;
        return;
    }

    float q0[4], q1[4];
    unpack_il(*reinterpret_cast<const uint4*>(&Qil[(size_t)n * HD_ + sl * 8]), q0, q1);

    float m0 = -INFINITY, m1 = -INFINITY;
    float den0 = 0.f, den1 = 0.f;
    float acc0[4] = {0.f, 0.f, 0.f, 0.f};
    float acc1[4] = {0.f, 0.f, 0.f, 0.f};

#if defined(__has_builtin)
#if __has_builtin(__builtin_amdgcn_cvt_pk_f32_fp8)
#define NFROW(node_id, a)                                                              \
    {                                                                                  \
        const unsigned u = *reinterpret_cast<const unsigned*>(                         \
            &nf8[(size_t)(node_id) * D_ + sl * 4]);                                    \
        const f32x2 lo = __builtin_amdgcn_cvt_pk_f32_fp8((int)u, false);               \
        const f32x2 hi = __builtin_amdgcn_cvt_pk_f32_fp8((int)u, true);                \
        a[0] += lo[0]; a[1] += lo[1]; a[2] += hi[0]; a[3] += hi[1];                    \
    }
#endif
#endif
#ifndef NFROW
#define NFROW(node_id, a)                                                              \
    {                                                                                  \
        const unsigned u = *reinterpret_cast<const unsigned*>(                         \
            &nf8[(size_t)(node_id) * D_ + sl * 4]);                                    \
        a[0] += fp82f(u & 0xffu);         a[1] += fp82f((u >> 8) & 0xffu);             \
        a[2] += fp82f((u >> 16) & 0xffu); a[3] += fp82f((u >> 24) & 0xffu);            \
    }
#endif

#define SMUPDATE(p0, p1, v0, v1, a)                                                    \
    {                                                                                  \
        const float l0 = p0 * P2L, l1 = p1 * P2L;                                      \
        if (l0 > m0 || l1 > m1) {                                                      \
            const float nm0 = fmaxf(m0, l0), nm1 = fmaxf(m1, l1);                      \
            const float c0 = exp2f(m0 - nm0), c1 = exp2f(m1 - nm1);                    \
            den0 *= c0; den1 *= c1;                                                    \
            _Pragma("unroll") for (int j = 0; j < 4; ++j) { acc0[j] *= c0; acc1[j] *= c1; } \
            m0 = nm0; m1 = nm1;                                                        \
        }                                                                              \
        const float e0 = exp2f(l0 - m0), e1 = exp2f(l1 - m1);                          \
        den0 += e0; den1 += e1;                                                        \
        _Pragma("unroll") for (int j = 0; j < 4; ++j) {                                \
            acc0[j] = fmaf(e0, v0[j] + a[j], acc0[j]);                                 \
            acc1[j] = fmaf(e1, v1[j] + a[j], acc1[j]);                                 \
        }                                                                              \
    }

    int i = start + half;
    uint4 rA = {0, 0, 0, 0}, rB = {0, 0, 0, 0};
    int wA = 0, wB = 0;
    if (i < end)     { rA = *reinterpret_cast<const uint4*>(recs + (size_t)i * 8);       wA = recs[(size_t)i * 8 + 4]; }
    if (i + 2 < end) { rB = *reinterpret_cast<const uint4*>(recs + (size_t)(i + 2) * 8); wB = recs[(size_t)(i + 2) * 8 + 4]; }

    // two edges of this half in flight, next pair's records prefetched
    for (; i + 2 < end; ) {
        const int sA = (int)rA.x, sB = (int)rB.x;
        const int4 mA = make_int4((int)rA.y, (int)rA.z, (int)rA.w, wA);
        const int4 mB = make_int4((int)rB.y, (int)rB.z, (int)rB.w, wB);

        const int ni = i + 4;
        const int pa = (ni < end)     ? ni     : i;   // clamped, stays in-bucket
        const int pb = (ni + 2 < end) ? ni + 2 : i;
        rA = *reinterpret_cast<const uint4*>(recs + (size_t)pa * 8); wA = recs[(size_t)pa * 8 + 4];
        rB = *reinterpret_cast<const uint4*>(recs + (size_t)pb * 8); wB = recs[(size_t)pb * 8 + 4];

        const uint4 kuA = *reinterpret_cast<const uint4*>(&KVil[(size_t)sA * 512 + sl * 8]);
        const uint4 vuA = *reinterpret_cast<const uint4*>(&KVil[(size_t)sA * 512 + 256 + sl * 8]);
        const uint4 kuB = *reinterpret_cast<const uint4*>(&KVil[(size_t)sB * 512 + sl * 8]);
        const uint4 vuB = *reinterpret_cast<const uint4*>(&KVil[(size_t)sB * 512 + 256 + sl * 8]);

        float aA[4] = {0.f, 0.f, 0.f, 0.f};
        float aB[4] = {0.f, 0.f, 0.f, 0.f};
        NFROW(mA.x, aA); NFROW(mA.y, aA); NFROW(mA.z, aA); NFROW(mA.w, aA);
        NFROW(mB.x, aB); NFROW(mB.y, aB); NFROW(mB.z, aB); NFROW(mB.w, aB);
#pragma unroll
        for (int j = 0; j < 4; ++j) { aA[j] *= 0.25f; aB[j] *= 0.25f; }

        float k0A[4], k1A[4], v0A[4], v1A[4];
        float k0B[4], k1B[4], v0B[4], v1B[4];
        unpack_il(kuA, k0A, k1A); unpack_il(vuA, v0A, v1A);
        unpack_il(kuB, k0B, k1B); unpack_il(vuB, v0B, v1B);

        float p0A = 0.f, p1A = 0.f, p0B = 0.f, p1B = 0.f;
#pragma unroll
        for (int j = 0; j < 4; ++j) {
            p0A = fmaf(q0[j], k0A[j] + aA[j], p0A);
            p1A = fmaf(q1[j], k1A[j] + aA[j], p1A);
            p0B = fmaf(q0[j], k0B[j] + aB[j], p0B);
            p1B = fmaf(q1[j], k1B[j] + aB[j], p1B);
        }
#pragma unroll
        for (int off = 1; off < 32; off <<= 1) {
            p0A += __shfl_xor(p0A, off, 64);
            p1A += __shfl_xor(p1A, off, 64);
            p0B += __shfl_xor(p0B, off, 64);
            p1B += __shfl_xor(p1B, off, 64);
        }
        SMUPDATE(p0A, p1A, v0A, v1A, aA);
        SMUPDATE(p0B, p1B, v0B, v1B, aB);
        i = ni;
    }
    for (; i < end; i += 2) {
        const uint4 r = *reinterpret_cast<const uint4*>(recs + (size_t)i * 8);
        const int w = recs[(size_t)i * 8 + 4];
        const int s = (int)r.x;
        const int4 mm = make_int4((int)r.y, (int)r.z, (int)r.w, w);
        const uint4 ku = *reinterpret_cast<const uint4*>(&KVil[(size_t)s * 512 + sl * 8]);
        const uint4 vu = *reinterpret_cast<const uint4*>(&KVil[(size_t)s * 512 + 256 + sl * 8]);
        float a[4] = {0.f, 0.f, 0.f, 0.f};
        NFROW(mm.x, a); NFROW(mm.y, a); NFROW(mm.z, a); NFROW(mm.w, a);
#pragma unroll
        for (int j = 0; j < 4; ++j) a[j] *= 0.25f;
        float k0[4], k1[4], v0[4], v1[4];
        unpack_il(ku, k0, k1); unpack_il(vu, v0, v1);
        float p0 = 0.f, p1 = 0.f;
#pragma unroll
        for (int j = 0; j < 4; ++j) {
            p0 = fmaf(q0[j], k0[j] + a[j], p0);
            p1 = fmaf(q1[j], k1[j] + a[j], p1);
        }
#pragma unroll
        for (int off = 1; off < 32; off <<= 1) {
            p0 += __shfl_xor(p0, off, 64);
            p1 += __shfl_xor(p1, off, 64);
        }
        SMUPDATE(p0, p1, v0, v1, a);
    }

    // ---- merge the two halves (2-way online-softmax merge) ----
    {
        const float M0 = fmaxf(m0, __shfl_xor(m0, 32, 64));
        const float M1 = fmaxf(m1, __shfl_xor(m1, 32, 64));
        const float c0 = exp2f(m0 - M0), c1 = exp2f(m1 - M1);
        den0 *= c0; den1 *= c1;
#pragma unroll
        for (int j = 0; j < 4; ++j) { acc0[j] *= c0; acc1[j] *= c1; }
        den0 += __shfl_xor(den0, 32, 64);
        den1 += __shfl_xor(den1, 32, 64);
#pragma unroll
        for (int j = 0; j < 4; ++j) {
            acc0[j] += __shfl_xor(acc0[j], 32, 64);
            acc1[j] += __shfl_xor(acc1[j], 32, 64);
        }
    }

    const float r0 = 1.f / (den0 + 1e-16f);
    const float r1 = 1.f / (den1 + 1e-16f);
    float4 ov;
    ov.x = half ? acc1[0] * r1 : acc0[0] * r0;
    ov.y = half ? acc1[1] * r1 : acc0[1] * r0;
    ov.z = half ? acc1[2] * r1 : acc0[2] * r0;
    ov.w = half ? acc1[3] * r1 : acc0[3] * r0;
    *reinterpret_cast<float4*>(&o[half * D_ + sl * 4]) = ov;
#undef NFROW
#undef SMUPDATE
}

extern "C" void kernel_launch(void* const* d_in, const int* in_sizes, int n_in,
                              void* d_out, int out_size, void* d_ws, size_t ws_size,
                              hipStream_t stream) {
    const float* nf  = (const float*)d_in[0];
    const int*   ei  = (const int*)d_in[1];   // [2, E]
    const int*   mp  = (const int*)d_in[2];   // [E, L]
    const float* Wq  = (const float*)d_in[3];
    const float* Wk  = (const float*)d_in[4];
    const float* Wv  = (const float*)d_in[5];
    float* out = (float*)d_out;

    const int N_nodes = in_sizes[0] / D_;
    const int E_edges = in_sizes[1] / 2;
    const int* src = ei;
    const int* dst = ei + E_edges;

    // workspace layout
    unsigned short* Qil  = (unsigned short*)d_ws;
    unsigned short* KVil = Qil + (size_t)N_nodes * HD_;          // [N][512]
    unsigned short* nfb  = KVil + (size_t)N_nodes * 512;
    unsigned char*  nf8  = (unsigned char*)(nfb + (size_t)N_nodes * D_);
    unsigned short* Wb   = (unsigned short*)(nf8 + (size_t)N_nodes * D_);  // [768][128]
    int* counts = (int*)(Wb + (size_t)768 * D_);
    int* ticket = counts + N_nodes;          // 8 ints (memset along with counts)
    int* offs   = ticket + 8;
    int* blksum = offs + N_nodes;            // up to 1024 chunk sums
    uintptr_t p = (uintptr_t)(blksum + 1024);
    p = (p + 31) & ~(uintptr_t)31;
    int* recs   = (int*)p;                   // [E][8] ints, 32B records

    const int nblk1 = (N_nodes + 1023) / 1024;
    const int n4 = N_nodes * D_ / 4;
    const int nfb_blocks = (n4 + 255) / 256;
    const int qkv_blocks = (N_nodes + QROWS - 1) / QROWS;

    hipMemsetAsync(counts, 0, ((size_t)N_nodes + 8) * sizeof(int), stream);

    // K1) prep (nf->bf16+fp8, W->Wb) + hist (fused)
    prep_hist_kernel<<<nfb_blocks + 384 + HIST_BLOCKS, 256, 0, stream>>>(
        nf, Wq, Wk, Wv, dst, nfb, nf8, Wb, counts, n4, E_edges);

    // K2) scan1 + scan2 fused (last workgroup finalizes)
    scan12_kernel<<<nblk1, 256, 0, stream>>>(counts, offs, blksum, ticket,
                                             N_nodes, nblk1);

    // K3) QKV via MFMA (64 rows/block) + scatter (32B records), fused to overlap
    qkv_scatter_kernel<<<qkv_blocks + SCAT_BLOCKS, 256, 0, stream>>>(
        nfb, Wb, Qil, KVil, dst, src, mp, offs, blksum, recs,
        N_nodes, E_edges, qkv_blocks);
    // offs[n] is now node n's chunk-local END; global end = offs[n] + blksum[n>>10]

    // K4) fused per-node: logits + online softmax + weighted sum + normalize
    node_fused_kernel<<<N_nodes, 64, 0, stream>>>(
        nf8, Qil, KVil, recs, offs, blksum, counts, out, N_nodes);
}

// Round 14
// 177.844 us; speedup vs baseline: 1.0298x; 1.0298x over previous
//
#include <hip/hip_runtime.h>
#include <hip/hip_bf16.h>
#include <hip/hip_fp8.h>

#define D_ 128
#define H_ 2
#define L_ 4
#define HD_ 256   // H_*D_
// (1/sqrt(128)) * log2(e): logits kept in base-2 domain, exp2f = bare v_exp_f32
#define P2L 0.12751743f

typedef __attribute__((ext_vector_type(8))) short bf16x8;
typedef __attribute__((ext_vector_type(4))) float f32x4;
typedef __attribute__((ext_vector_type(2))) float f32x2;

__device__ __forceinline__ unsigned short f2bf(float x) {
    __hip_bfloat16 b = __float2bfloat16(x);
    return *reinterpret_cast<unsigned short*>(&b);
}
__device__ __forceinline__ float bf2f(unsigned short u) {
    return __uint_as_float(((unsigned)u) << 16);
}
__device__ __forceinline__ unsigned char f2fp8(float x) {
    __hip_fp8_e4m3 t(x);
    return (unsigned char)t.__x;
}
__device__ __forceinline__ float fp82f(unsigned u) {
    __hip_fp8_e4m3 t; t.__x = (__hip_fp8_storage_t)u; return (float)t;
}
// unpack 8 interleaved bf16 (d*2+h layout) -> h0[4], h1[4]
__device__ __forceinline__ void unpack_il(const uint4 v, float* h0, float* h1) {
    const unsigned short* u = reinterpret_cast<const unsigned short*>(&v);
#pragma unroll
    for (int j = 0; j < 4; ++j) { h0[j] = bf2f(u[2 * j]); h1[j] = bf2f(u[2 * j + 1]); }
}

// ---------- K1: prep (nf->fp8, W->Wb) AND hist, fused by block range ----------
#define HIST_BLOCKS 512
__global__ __launch_bounds__(256)
void prep_hist_kernel(const float* __restrict__ nf,
                      const float* __restrict__ Wq, const float* __restrict__ Wk,
                      const float* __restrict__ Wv, const int* __restrict__ dst,
                      unsigned char* __restrict__ nf8,
                      unsigned short* __restrict__ Wb, int* __restrict__ counts,
                      int n4, int E_) {
    const int nfbB = (n4 + 255) / 256;
    const int bid = blockIdx.x;
    if (bid < nfbB) {
        const int i = bid * 256 + threadIdx.x;
        if (i < n4) {
            const float4 v = reinterpret_cast<const float4*>(nf)[i];
            const unsigned p8 = (unsigned)f2fp8(v.x) | ((unsigned)f2fp8(v.y) << 8) |
                                ((unsigned)f2fp8(v.z) << 16) | ((unsigned)f2fp8(v.w) << 24);
            reinterpret_cast<unsigned*>(nf8)[i] = p8;
        }
    } else if (bid < nfbB + 384) {
        const int b = bid - nfbB;                     // 0..383
        const int n = b * 2 + (threadIdx.x >> 7);     // 0..767
        const int k = threadIdx.x & 127;
        const float* W = (n < 256) ? Wq : (n < 512) ? Wk : Wv;
        const int c = n & 255;
        Wb[(size_t)n * 128 + k] = f2bf(W[(size_t)k * HD_ + c]);
    } else {
        const int b = bid - nfbB - 384;               // 0..HIST_BLOCKS-1
        const int nquad = E_ >> 2;
        for (int i = b * 256 + threadIdx.x; i < nquad; i += HIST_BLOCKS * 256) {
            const int4 d4 = reinterpret_cast<const int4*>(dst)[i];
            atomicAdd(&counts[d4.x], 1);
            atomicAdd(&counts[d4.y], 1);
            atomicAdd(&counts[d4.z], 1);
            atomicAdd(&counts[d4.w], 1);
        }
        if (b == 0 && (int)threadIdx.x < (E_ & 3))
            atomicAdd(&counts[dst[(E_ & ~3) + threadIdx.x]], 1);
    }
}

// ---------- K2: scan1 — per-chunk (1024) exclusive scan of counts ----------
__global__ __launch_bounds__(256)
void scan1_kernel(const int* __restrict__ counts, int* __restrict__ offs,
                  int* __restrict__ blksum, int n) {
    __shared__ int sdata[256];
    const int t = threadIdx.x;
    const int base = blockIdx.x * 1024;
    int v[4]; int sum = 0;
#pragma unroll
    for (int j = 0; j < 4; ++j) {
        int idx = base + t * 4 + j;
        v[j] = (idx < n) ? counts[idx] : 0;
        sum += v[j];
    }
    sdata[t] = sum;
    __syncthreads();
    for (int off = 1; off < 256; off <<= 1) {
        int x = (t >= off) ? sdata[t - off] : 0;
        __syncthreads();
        sdata[t] += x;
        __syncthreads();
    }
    if (t == 255) blksum[blockIdx.x] = sdata[255];
    int run = sdata[t] - sum;
#pragma unroll
    for (int j = 0; j < 4; ++j) {
        int idx = base + t * 4 + j;
        if (idx < n) offs[idx] = run;
        run += v[j];
    }
}

// ---------- K3: scan2 — single-wave shuffle prefix scan over chunk sums ----------
__global__ __launch_bounds__(64)
void scan2_kernel(int* __restrict__ blksum, int nblk) {
    const int lane = threadIdx.x;
    int carry = 0;
    for (int base = 0; base < nblk; base += 64) {
        const int idx = base + lane;
        int v = (idx < nblk) ? blksum[idx] : 0;
        int inc = v;
#pragma unroll
        for (int off = 1; off < 64; off <<= 1) {
            int x = __shfl_up(inc, off, 64);
            if (lane >= off) inc += x;
        }
        if (idx < nblk) blksum[idx] = carry + inc - v;   // exclusive
        carry += __shfl(inc, 63, 64);
    }
}

// ---------- K4: MFMA QKV (64 rows/block, A from f32 nf) AND scatter, fused ----------
#define SCAT_BLOCKS 1024
#define QROWS 64
__global__ __launch_bounds__(256)
void qkv_scatter_kernel(const float* __restrict__ nf,
                        const unsigned short* __restrict__ Wb,
                        unsigned short* __restrict__ Qil,
                        unsigned short* __restrict__ KVil,   // [node][512]: K il | V il
                        const int* __restrict__ dst, const int* __restrict__ src,
                        const int* __restrict__ mp, int* __restrict__ offs,
                        const int* __restrict__ blksum,
                        int* __restrict__ recs,             // [E][8] ints (32B records)
                        int n_nodes, int E_, int qkv_blocks) {
    __shared__ unsigned short sS[QROWS][264];

    if ((int)blockIdx.x >= qkv_blocks) {
        // ---- scatter: sort edge payload by dst; one 32B record per edge ----
        const int b = blockIdx.x - qkv_blocks;
        for (int i = b * 256 + threadIdx.x; i < E_; i += SCAT_BLOCKS * 256) {
            const int d = dst[i];
            const int pos = atomicAdd(&offs[d], 1) + blksum[d >> 10];
            const int4 m4 = *reinterpret_cast<const int4*>(&mp[(size_t)i * L_]);
            uint4 u0;
            u0.x = (unsigned)src[i]; u0.y = (unsigned)m4.x;
            u0.z = (unsigned)m4.y;   u0.w = (unsigned)m4.z;
            *reinterpret_cast<uint4*>(recs + (size_t)pos * 8) = u0;
            recs[(size_t)pos * 8 + 4] = m4.w;
        }
        return;
    }

    // ---- qkv: block owns 64 node-rows; A fragments converted f32->bf16 in-reg ----
    const int tid  = threadIdx.x;
    const int lane = tid & 63;
    const int wv   = tid >> 6;
    const int m0   = blockIdx.x * QROWS;
    const int r16  = lane & 15;
    const int kg   = lane >> 4;

    bf16x8 afrag[4][4];
#pragma unroll
    for (int ms = 0; ms < 4; ++ms) {
        int arow = m0 + ms * 16 + r16;
        if (arow >= n_nodes) arow = n_nodes - 1;
        const float* aptr = nf + (size_t)arow * D_ + kg * 8;
#pragma unroll
        for (int kb = 0; kb < 4; ++kb) {
            const float4 fa = *reinterpret_cast<const float4*>(aptr + kb * 32);
            const float4 fb = *reinterpret_cast<const float4*>(aptr + kb * 32 + 4);
            bf16x8 t;
            t[0] = (short)f2bf(fa.x); t[1] = (short)f2bf(fa.y);
            t[2] = (short)f2bf(fa.z); t[3] = (short)f2bf(fa.w);
            t[4] = (short)f2bf(fb.x); t[5] = (short)f2bf(fb.y);
            t[6] = (short)f2bf(fb.z); t[7] = (short)f2bf(fb.w);
            afrag[ms][kb] = t;
        }
    }

    for (int p = 0; p < 3; ++p) {           // phase: 0=Q, 1=K, 2=V
#pragma unroll
        for (int j = 0; j < 4; ++j) {
            const int n0 = p * 256 + (wv * 4 + j) * 16;
            const unsigned short* bptr = Wb + (size_t)(n0 + r16) * D_ + kg * 8;
            bf16x8 b0 = *reinterpret_cast<const bf16x8*>(bptr);
            bf16x8 b1 = *reinterpret_cast<const bf16x8*>(bptr + 32);
            bf16x8 b2 = *reinterpret_cast<const bf16x8*>(bptr + 64);
            bf16x8 b3 = *reinterpret_cast<const bf16x8*>(bptr + 96);
            f32x4 acc[4];
#pragma unroll
            for (int ms = 0; ms < 4; ++ms) { acc[ms] = {0.f, 0.f, 0.f, 0.f}; }
#pragma unroll
            for (int ms = 0; ms < 4; ++ms) {
                acc[ms] = __builtin_amdgcn_mfma_f32_16x16x32_bf16(afrag[ms][0], b0, acc[ms], 0, 0, 0);
                acc[ms] = __builtin_amdgcn_mfma_f32_16x16x32_bf16(afrag[ms][1], b1, acc[ms], 0, 0, 0);
                acc[ms] = __builtin_amdgcn_mfma_f32_16x16x32_bf16(afrag[ms][2], b2, acc[ms], 0, 0, 0);
                acc[ms] = __builtin_amdgcn_mfma_f32_16x16x32_bf16(afrag[ms][3], b3, acc[ms], 0, 0, 0);
            }
            const int ln = (n0 & 255) + r16;                   // local col 0..255
            const int il = ((ln & 127) << 1) | ((ln >> 7) & 1);
#pragma unroll
            for (int ms = 0; ms < 4; ++ms)
#pragma unroll
                for (int jj = 0; jj < 4; ++jj)
                    sS[ms * 16 + kg * 4 + jj][il] = f2bf(acc[ms][jj]);
        }
        __syncthreads();
        // flush QROWS rows x 256 cols (uint2 = 4 bf16)
        for (int i2 = tid; i2 < QROWS * 64; i2 += 256) {
            const int r = i2 >> 6, c4 = i2 & 63;
            const int node = m0 + r;
            if (node < n_nodes) {
                const uint2 val = *reinterpret_cast<const uint2*>(&sS[r][c4 * 4]);
                if (p == 0)
                    *reinterpret_cast<uint2*>(&Qil[(size_t)node * HD_ + c4 * 4]) = val;
                else if (p == 1)
                    *reinterpret_cast<uint2*>(&KVil[(size_t)node * 512 + c4 * 4]) = val;
                else
                    *reinterpret_cast<uint2*>(&KVil[(size_t)node * 512 + 256 + c4 * 4]) = val;
            }
        }
        __syncthreads();
    }
}

// ---------- K5: fused per-node, 2-wave blocks, rotated record prefetch ----------
__global__ __launch_bounds__(128)
void node_fused_kernel(const unsigned char* __restrict__ nf8,
                       const unsigned short* __restrict__ Qil,
                       const unsigned short* __restrict__ KVil,
                       const int* __restrict__ recs,    // [E][8] ints
                       const int* __restrict__ ends,    // chunk-local ends
                       const int* __restrict__ blksum,  // chunk bases
                       const int* __restrict__ counts,
                       float* __restrict__ out,
                       int n_nodes) {
    const int lane = threadIdx.x & 63;
    const int half = lane >> 5;          // sub-wave id
    const int sl   = lane & 31;          // sub-lane: owns dims 4sl..4sl+3
    const int n = __builtin_amdgcn_readfirstlane(
        blockIdx.x * 2 + (threadIdx.x >> 6));
    if (n >= n_nodes) return;

    const int deg = counts[n];
    const int end = ends[n] + blksum[n >> 10];
    const int start = end - deg;
    float* o = out + (size_t)n * HD_;

    if (deg == 0) {
        const float4 z = {0.f, 0.f, 0.f, 0.f};
        *reinterpret_cast<float4*>(&o[half * D_ + sl * 4]) = z;
        return;
    }

    float q0[4], q1[4];
    unpack_il(*reinterpret_cast<const uint4*>(&Qil[(size_t)n * HD_ + sl * 8]), q0, q1);

    float m0 = -INFINITY, m1 = -INFINITY;
    float den0 = 0.f, den1 = 0.f;
    float acc0[4] = {0.f, 0.f, 0.f, 0.f};
    float acc1[4] = {0.f, 0.f, 0.f, 0.f};

#if defined(__has_builtin)
#if __has_builtin(__builtin_amdgcn_cvt_pk_f32_fp8)
#define NFROW(node_id, a)                                                              \
    {                                                                                  \
        const unsigned u = *reinterpret_cast<const unsigned*>(                         \
            &nf8[(size_t)(node_id) * D_ + sl * 4]);                                    \
        const f32x2 lo = __builtin_amdgcn_cvt_pk_f32_fp8((int)u, false);               \
        const f32x2 hi = __builtin_amdgcn_cvt_pk_f32_fp8((int)u, true);                \
        a[0] += lo[0]; a[1] += lo[1]; a[2] += hi[0]; a[3] += hi[1];                    \
    }
#endif
#endif
#ifndef NFROW
#define NFROW(node_id, a)                                                              \
    {                                                                                  \
        const unsigned u = *reinterpret_cast<const unsigned*>(                         \
            &nf8[(size_t)(node_id) * D_ + sl * 4]);                                    \
        a[0] += fp82f(u & 0xffu);         a[1] += fp82f((u >> 8) & 0xffu);             \
        a[2] += fp82f((u >> 16) & 0xffu); a[3] += fp82f((u >> 24) & 0xffu);            \
    }
#endif

#define SMUPDATE(p0, p1, v0, v1, a)                                                    \
    {                                                                                  \
        const float l0 = p0 * P2L, l1 = p1 * P2L;                                      \
        if (l0 > m0 || l1 > m1) {                                                      \
            const float nm0 = fmaxf(m0, l0), nm1 = fmaxf(m1, l1);                      \
            const float c0 = exp2f(m0 - nm0), c1 = exp2f(m1 - nm1);                    \
            den0 *= c0; den1 *= c1;                                                    \
            _Pragma("unroll") for (int j = 0; j < 4; ++j) { acc0[j] *= c0; acc1[j] *= c1; } \
            m0 = nm0; m1 = nm1;                                                        \
        }                                                                              \
        const float e0 = exp2f(l0 - m0), e1 = exp2f(l1 - m1);                          \
        den0 += e0; den1 += e1;                                                        \
        _Pragma("unroll") for (int j = 0; j < 4; ++j) {                                \
            acc0[j] = fmaf(e0, v0[j] + a[j], acc0[j]);                                 \
            acc1[j] = fmaf(e1, v1[j] + a[j], acc1[j]);                                 \
        }                                                                              \
    }

    int i = start + half;
    uint4 rA = {0, 0, 0, 0}, rB = {0, 0, 0, 0};
    int wA = 0, wB = 0;
    if (i < end)     { rA = *reinterpret_cast<const uint4*>(recs + (size_t)i * 8);       wA = recs[(size_t)i * 8 + 4]; }
    if (i + 2 < end) { rB = *reinterpret_cast<const uint4*>(recs + (size_t)(i + 2) * 8); wB = recs[(size_t)(i + 2) * 8 + 4]; }

    // two edges of this half in flight, next pair's records prefetched
    for (; i + 2 < end; ) {
        const int sA = (int)rA.x, sB = (int)rB.x;
        const int4 mA = make_int4((int)rA.y, (int)rA.z, (int)rA.w, wA);
        const int4 mB = make_int4((int)rB.y, (int)rB.z, (int)rB.w, wB);

        const int ni = i + 4;
        const int pa = (ni < end)     ? ni     : i;   // clamped, stays in-bucket
        const int pb = (ni + 2 < end) ? ni + 2 : i;
        rA = *reinterpret_cast<const uint4*>(recs + (size_t)pa * 8); wA = recs[(size_t)pa * 8 + 4];
        rB = *reinterpret_cast<const uint4*>(recs + (size_t)pb * 8); wB = recs[(size_t)pb * 8 + 4];

        const uint4 kuA = *reinterpret_cast<const uint4*>(&KVil[(size_t)sA * 512 + sl * 8]);
        const uint4 vuA = *reinterpret_cast<const uint4*>(&KVil[(size_t)sA * 512 + 256 + sl * 8]);
        const uint4 kuB = *reinterpret_cast<const uint4*>(&KVil[(size_t)sB * 512 + sl * 8]);
        const uint4 vuB = *reinterpret_cast<const uint4*>(&KVil[(size_t)sB * 512 + 256 + sl * 8]);

        float aA[4] = {0.f, 0.f, 0.f, 0.f};
        float aB[4] = {0.f, 0.f, 0.f, 0.f};
        NFROW(mA.x, aA); NFROW(mA.y, aA); NFROW(mA.z, aA); NFROW(mA.w, aA);
        NFROW(mB.x, aB); NFROW(mB.y, aB); NFROW(mB.z, aB); NFROW(mB.w, aB);
#pragma unroll
        for (int j = 0; j < 4; ++j) { aA[j] *= 0.25f; aB[j] *= 0.25f; }

        float k0A[4], k1A[4], v0A[4], v1A[4];
        float k0B[4], k1B[4], v0B[4], v1B[4];
        unpack_il(kuA, k0A, k1A); unpack_il(vuA, v0A, v1A);
        unpack_il(kuB, k0B, k1B); unpack_il(vuB, v0B, v1B);

        float p0A = 0.f, p1A = 0.f, p0B = 0.f, p1B = 0.f;
#pragma unroll
        for (int j = 0; j < 4; ++j) {
            p0A = fmaf(q0[j], k0A[j] + aA[j], p0A);
            p1A = fmaf(q1[j], k1A[j] + aA[j], p1A);
            p0B = fmaf(q0[j], k0B[j] + aB[j], p0B);
            p1B = fmaf(q1[j], k1B[j] + aB[j], p1B);
        }
#pragma unroll
        for (int off = 1; off < 32; off <<= 1) {
            p0A += __shfl_xor(p0A, off, 64);
            p1A += __shfl_xor(p1A, off, 64);
            p0B += __shfl_xor(p0B, off, 64);
            p1B += __shfl_xor(p1B, off, 64);
        }
        SMUPDATE(p0A, p1A, v0A, v1A, aA);
        SMUPDATE(p0B, p1B, v0B, v1B, aB);
        i = ni;
    }
    for (; i < end; i += 2) {
        const uint4 r = *reinterpret_cast<const uint4*>(recs + (size_t)i * 8);
        const int w = recs[(size_t)i * 8 + 4];
        const int s = (int)r.x;
        const int4 mm = make_int4((int)r.y, (int)r.z, (int)r.w, w);
        const uint4 ku = *reinterpret_cast<const uint4*>(&KVil[(size_t)s * 512 + sl * 8]);
        const uint4 vu = *reinterpret_cast<const uint4*>(&KVil[(size_t)s * 512 + 256 + sl * 8]);
        float a[4] = {0.f, 0.f, 0.f, 0.f};
        NFROW(mm.x, a); NFROW(mm.y, a); NFROW(mm.z, a); NFROW(mm.w, a);
#pragma unroll
        for (int j = 0; j < 4; ++j) a[j] *= 0.25f;
        float k0[4], k1[4], v0[4], v1[4];
        unpack_il(ku, k0, k1); unpack_il(vu, v0, v1);
        float p0 = 0.f, p1 = 0.f;
#pragma unroll
        for (int j = 0; j < 4; ++j) {
            p0 = fmaf(q0[j], k0[j] + a[j], p0);
            p1 = fmaf(q1[j], k1[j] + a[j], p1);
        }
#pragma unroll
        for (int off = 1; off < 32; off <<= 1) {
            p0 += __shfl_xor(p0, off, 64);
            p1 += __shfl_xor(p1, off, 64);
        }
        SMUPDATE(p0, p1, v0, v1, a);
    }

    // ---- merge the two halves (2-way online-softmax merge) ----
    {
        const float M0 = fmaxf(m0, __shfl_xor(m0, 32, 64));
        const float M1 = fmaxf(m1, __shfl_xor(m1, 32, 64));
        const float c0 = exp2f(m0 - M0), c1 = exp2f(m1 - M1);
        den0 *= c0; den1 *= c1;
#pragma unroll
        for (int j = 0; j < 4; ++j) { acc0[j] *= c0; acc1[j] *= c1; }
        den0 += __shfl_xor(den0, 32, 64);
        den1 += __shfl_xor(den1, 32, 64);
#pragma unroll
        for (int j = 0; j < 4; ++j) {
            acc0[j] += __shfl_xor(acc0[j], 32, 64);
            acc1[j] += __shfl_xor(acc1[j], 32, 64);
        }
    }

    const float r0 = 1.f / (den0 + 1e-16f);
    const float r1 = 1.f / (den1 + 1e-16f);
    float4 ov;
    ov.x = half ? acc1[0] * r1 : acc0[0] * r0;
    ov.y = half ? acc1[1] * r1 : acc0[1] * r0;
    ov.z = half ? acc1[2] * r1 : acc0[2] * r0;
    ov.w = half ? acc1[3] * r1 : acc0[3] * r0;
    *reinterpret_cast<float4*>(&o[half * D_ + sl * 4]) = ov;
#undef NFROW
#undef SMUPDATE
}

extern "C" void kernel_launch(void* const* d_in, const int* in_sizes, int n_in,
                              void* d_out, int out_size, void* d_ws, size_t ws_size,
                              hipStream_t stream) {
    const float* nf  = (const float*)d_in[0];
    const int*   ei  = (const int*)d_in[1];   // [2, E]
    const int*   mp  = (const int*)d_in[2];   // [E, L]
    const float* Wq  = (const float*)d_in[3];
    const float* Wk  = (const float*)d_in[4];
    const float* Wv  = (const float*)d_in[5];
    float* out = (float*)d_out;

    const int N_nodes = in_sizes[0] / D_;
    const int E_edges = in_sizes[1] / 2;
    const int* src = ei;
    const int* dst = ei + E_edges;

    // workspace layout
    unsigned short* Qil  = (unsigned short*)d_ws;
    unsigned short* KVil = Qil + (size_t)N_nodes * HD_;          // [N][512]
    unsigned char*  nf8  = (unsigned char*)(KVil + (size_t)N_nodes * 512);
    unsigned short* Wb   = (unsigned short*)(nf8 + (size_t)N_nodes * D_);  // [768][128]
    int* counts = (int*)(Wb + (size_t)768 * D_);
    int* offs   = counts + N_nodes;
    int* blksum = offs + N_nodes;            // up to 1024 chunk sums
    uintptr_t p = (uintptr_t)(blksum + 1024);
    p = (p + 31) & ~(uintptr_t)31;
    int* recs   = (int*)p;                   // [E][8] ints, 32B records

    const int nblk1 = (N_nodes + 1023) / 1024;
    const int n4 = N_nodes * D_ / 4;
    const int nfb_blocks = (n4 + 255) / 256;
    const int qkv_blocks = (N_nodes + QROWS - 1) / QROWS;

    hipMemsetAsync(counts, 0, (size_t)N_nodes * sizeof(int), stream);

    // K1) prep (nf->fp8, W->Wb) + hist (fused)
    prep_hist_kernel<<<nfb_blocks + 384 + HIST_BLOCKS, 256, 0, stream>>>(
        nf, Wq, Wk, Wv, dst, nf8, Wb, counts, n4, E_edges);

    // K2) scan1 over counts (chunk-local)
    scan1_kernel<<<nblk1, 256, 0, stream>>>(counts, offs, blksum, N_nodes);

    // K3) scan2 over chunk sums
    scan2_kernel<<<1, 64, 0, stream>>>(blksum, nblk1);

    // K4) QKV via MFMA (64 rows/block, A from f32 nf) + scatter, fused to overlap
    qkv_scatter_kernel<<<qkv_blocks + SCAT_BLOCKS, 256, 0, stream>>>(
        nf, Wb, Qil, KVil, dst, src, mp, offs, blksum, recs,
        N_nodes, E_edges, qkv_blocks);
    // offs[n] is now node n's chunk-local END; global end = offs[n] + blksum[n>>10]

    // K5) fused per-node: logits + online softmax + weighted sum + normalize
    node_fused_kernel<<<(N_nodes + 1) / 2, 128, 0, stream>>>(
        nf8, Qil, KVil, recs, offs, blksum, counts, out, N_nodes);
}